// Round 10
// baseline (873.102 us; speedup 1.0000x reference)
//
#include <hip/hip_runtime.h>

#define D_   32
#define H_   256
#define W_   256
#define HW_  (H_ * W_)
#define DHW_ (D_ * H_ * W_)   // 2097152
#define V_   40000
#define CIN  16
#define COUT 32
#define P_   32
#define EPS_ 1e-5f

#define TD 2
#define TH 8
#define TW 32
#define NTX (W_ / TW)          // 8
#define NTY (H_ / TH)          // 32
#define NTZ (D_ / TD)          // 16
#define NT  (NTX * NTY * NTZ)  // 4096 tiles
#define TPOS (TD * TH * TW)    // 512
#define OH 8                   // channels per quarter
#define NQ (COUT / OH)         // 4
#define TROW 9                 // padded LDS row stride (odd -> conflict-free strided reads)
#define TCT 512                // threads per tile_conv block (8 waves)
#define SSLOT 64               // stats de-contention slots per channel
#define TAPC 640               // LDS-staged taps per tile (mean ~257; overflow reads global)
#define VBLK ((V_ + 255) / 256)            // 157 voxel blocks
#define WTN  (NQ * 27 * 4 * OH)            // 3456 transpose items
#define WTBLK ((WTN + 255) / 256)          // 14 transpose blocks
#define FPBLK ((V_ * 4 + 255) / 256)       // 625 featpack blocks
#define NBLK_A (VBLK + WTBLK + FPBLK)      // 796 prep blocks (<= 1024 co-resident @4/CU)

// Manual grid barrier: safe because grid(796) < guaranteed-resident(1024 @ 4 blocks/CU
// via __launch_bounds__(256,4)). Device-scope RMW spin (volatile load would be unsafe
// across non-coherent XCD L2s). Release fence before arrive makes prior plain writes
// (cursor) visible to later phases' atomics.
__device__ __forceinline__ void gbar(int* bar, int target) {
    __syncthreads();
    if (threadIdx.x == 0) {
        __threadfence();
        atomicAdd(bar, 1);
        while (atomicAdd(bar, 0) < target) __builtin_amdgcn_s_sleep(15);
        __threadfence();
    }
    __syncthreads();
}

// ---------- K_A: zero | count/WT/featpack | scan | fill — one dispatch ----------
__global__ void __launch_bounds__(256, 4) prep_all_kernel(
    const int* __restrict__ idxs, int* __restrict__ tapcnt,
    const float* __restrict__ conv_w, float4* __restrict__ wt4,
    const float* __restrict__ vox, float4* __restrict__ feats4,
    int* __restrict__ starts, int* __restrict__ cursor,
    float* __restrict__ stats, int* __restrict__ tapbuf, int* __restrict__ bar)
{
    __shared__ int part[256];
    int b = blockIdx.x, t = threadIdx.x;
    int gid = b * 256 + t;

    // phase 0: zero tapcnt (4096 ints) + stats (4096 floats)
    if (gid < NT) tapcnt[gid] = 0;
    else if (gid < NT + 2 * COUT * SSLOT) stats[gid - NT] = 0.f;
    gbar(bar, NBLK_A);

    // phase 1: block roles (no early returns — all blocks must reach every barrier)
    if (b < VBLK) {
        int v = gid;
        if (v < V_) {
            int w = idxs[3 * v], h = idxs[3 * v + 1], d = idxs[3 * v + 2];
            if ((unsigned)w < W_ && (unsigned)h < H_ && (unsigned)d < D_) {
                int dlo = max(d - 1, 0), dhi = min(d + 1, D_ - 1);
                int hlo = max(h - 1, 0), hhi = min(h + 1, H_ - 1);
                int wlo = max(w - 1, 0), whi = min(w + 1, W_ - 1);
                for (int tz = dlo / TD; tz <= dhi / TD; ++tz) {
                    int zl = max(dlo, tz * TD), zh = min(dhi, tz * TD + TD - 1);
                    for (int ty = hlo / TH; ty <= hhi / TH; ++ty) {
                        int yl = max(hlo, ty * TH), yh = min(hhi, ty * TH + TH - 1);
                        for (int tx = wlo / TW; tx <= whi / TW; ++tx) {
                            int xl = max(wlo, tx * TW), xh = min(whi, tx * TW + TW - 1);
                            int cnt = (zh - zl + 1) * (yh - yl + 1) * (xh - xl + 1);
                            atomicAdd(&tapcnt[tz * NTY * NTX + ty * NTX + tx], cnt);
                        }
                    }
                }
            }
        }
    } else if (b < VBLK + WTBLK) {
        int n = (b - VBLK) * 256 + t;
        if (n < WTN) {
            int oo = n & 7;
            int jj = (n >> 3) & 3;
            int m  = n >> 5;            // quarter*27 + k
            int k  = m % 27;
            int quarter = m / 27;
            int o = quarter * OH + oo;
            float4 wv;
            wv.x = conv_w[(o * CIN + 4 * jj + 0) * 27 + k];
            wv.y = conv_w[(o * CIN + 4 * jj + 1) * 27 + k];
            wv.z = conv_w[(o * CIN + 4 * jj + 2) * 27 + k];
            wv.w = conv_w[(o * CIN + 4 * jj + 3) * 27 + k];
            wt4[n] = wv;
        }
    } else {
        // featpack: (b - VBLK - WTBLK)*256 + t in [0, V_*4) exactly (625*256)
        int idx = (b - VBLK - WTBLK) * 256 + t;
        int v = idx >> 2, q = idx & 3;
        const float* base = vox + ((size_t)v * CIN + 4 * q) * P_;
        float m[4];
#pragma unroll
        for (int c = 0; c < 4; ++c) {
            const float4* p = (const float4*)(base + c * P_);
            float s = 0.f;
#pragma unroll
            for (int j = 0; j < P_ / 4; ++j) {
                float4 tv = p[j];
                s += tv.x + tv.y + tv.z + tv.w;
            }
            m[c] = s * (1.0f / (float)P_);
        }
        feats4[v * 4 + q] = make_float4(m[0], m[1], m[2], m[3]);
    }
    gbar(bar, 2 * NBLK_A);

    // phase 2: exclusive prefix over 4096 tiles (block 0 only; others sleep in gbar)
    if (b == 0) {
        int base = t * 16;
        int s = 0;
        for (int j = 0; j < 16; ++j) s += tapcnt[base + j];
        part[t] = s;
        __syncthreads();
        for (int off = 1; off < 256; off <<= 1) {
            int val = part[t];
            int add = (t >= off) ? part[t - off] : 0;
            __syncthreads();
            part[t] = val + add;
            __syncthreads();
        }
        int run = (t > 0) ? part[t - 1] : 0;
        for (int j = 0; j < 16; ++j) {
            starts[base + j] = run;
            cursor[base + j] = run;
            run += tapcnt[base + j];
        }
    }
    gbar(bar, 3 * NBLK_A);   // gbar's release fence publishes block 0's starts/cursor

    // phase 3: tap fill (cursor accessed via device-scope RMW -> coherent)
    if (b < VBLK) {
        int v = gid;
        if (v < V_) {
            int w = idxs[3 * v], h = idxs[3 * v + 1], d = idxs[3 * v + 2];
            if ((unsigned)w < W_ && (unsigned)h < H_ && (unsigned)d < D_) {
                int dlo = max(d - 1, 0), dhi = min(d + 1, D_ - 1);
                int hlo = max(h - 1, 0), hhi = min(h + 1, H_ - 1);
                int wlo = max(w - 1, 0), whi = min(w + 1, W_ - 1);
                for (int tz = dlo / TD; tz <= dhi / TD; ++tz) {
                    int zl = max(dlo, tz * TD), zh = min(dhi, tz * TD + TD - 1);
                    for (int ty = hlo / TH; ty <= hhi / TH; ++ty) {
                        int yl = max(hlo, ty * TH), yh = min(hhi, ty * TH + TH - 1);
                        for (int tx = wlo / TW; tx <= whi / TW; ++tx) {
                            int xl = max(wlo, tx * TW), xh = min(whi, tx * TW + TW - 1);
                            int cnt = (zh - zl + 1) * (yh - yl + 1) * (xh - xl + 1);
                            int p = atomicAdd(&cursor[tz * NTY * NTX + ty * NTX + tx], cnt);
                            for (int dq = zl; dq <= zh; ++dq)
                                for (int hq = yl; hq <= yh; ++hq)
                                    for (int wq = xl; wq <= xh; ++wq) {
                                        int k = ((d - dq + 1) * 3 + (h - hq + 1)) * 3
                                              + (w - wq + 1);
                                        int pos = ((dq & (TD - 1)) * TH + (hq & (TH - 1))) * TW
                                                + (wq & (TW - 1));
                                        tapbuf[p++] = (v << 14) | (k << 9) | pos;
                                    }
                        }
                    }
                }
            }
        }
    }
}

// ---------- K5: tile conv (BYTE-IDENTICAL to R9 — control) ----------
__global__ void __launch_bounds__(TCT, 8) tile_conv_kernel(
    const float4* __restrict__ feats4, const float4* __restrict__ wt4,
    const int* __restrict__ tapstart, const int* __restrict__ tapcnt,
    const int* __restrict__ tapbuf, float* __restrict__ stats,
    float* __restrict__ out)
{
    __shared__ float  tile[TPOS * TROW];   // 18432 B
    __shared__ float4 wsm4[27 * 4 * OH];   // 13824 B, [k*32 + jj*8 + oo]
    __shared__ int    taps_l[TAPC];        //  2560 B (staging)
    __shared__ int    taps_s[TAPC];        //  2560 B (k-sorted)
    __shared__ int    khist[32];           //   128 B (hist -> cursor)
    __shared__ float  wsum[8][OH], wsq[8][OH];

    int t = threadIdx.x;
    int tile_id = blockIdx.x;
    int gs = tapstart[tile_id];
    int nt = tapcnt[tile_id];
    int tx = tile_id % NTX, ty = (tile_id / NTX) % NTY, tz = tile_id / (NTX * NTY);
    int w0 = tx * TW, h0 = ty * TH, d0 = tz * TD;
    int sl = tile_id & (SSLOT - 1);

    // stage tap list + counting-sort by k (done once, reused by all 4 quarters)
    int ntl = min(nt, TAPC);
    if (t < 32) khist[t] = 0;
    for (int j = t; j < ntl; j += TCT) taps_l[j] = tapbuf[gs + j];
    __syncthreads();
    for (int j = t; j < ntl; j += TCT)
        atomicAdd(&khist[(taps_l[j] >> 9) & 31], 1);
    __syncthreads();
    if (t < 64) {                           // wave-0 exclusive scan over 27 bins
        int x = (t < 27) ? khist[t] : 0;
        int orig = x;
#pragma unroll
        for (int off = 1; off < 32; off <<= 1) {
            int y = __shfl_up(x, off);
            if (t >= off) x += y;
        }
        if (t < 27) khist[t] = x - orig;    // becomes the scatter cursor
    }
    __syncthreads();
    for (int j = t; j < ntl; j += TCT) {
        int tap = taps_l[j];
        int p = atomicAdd(&khist[(tap >> 9) & 31], 1);
        taps_s[p] = tap;
    }
    __syncthreads();

    int oo = t & 7, slot = t >> 3;          // scatter + D1 mapping
    int wave = t >> 6, lane = t & 63;
    int wl = t & 31, rem = t >> 5;          // D2 mapping (rem 0..15)
    size_t outb = (size_t)(d0 + (rem >> 3)) * HW_ + (size_t)(h0 + (rem & 7)) * W_
                + (size_t)(w0 + wl);
    int posD = (rem * TW + wl) * TROW;

#pragma unroll
    for (int qq = 0; qq < NQ; ++qq) {
        int obase = qq * OH;
        // stage: zero tile + this quarter's weights (linear layout)
        for (int j = t; j < TPOS * TROW / 4; j += TCT)
            ((float4*)tile)[j] = make_float4(0, 0, 0, 0);
        for (int j = t; j < 27 * 4 * OH; j += TCT)
            wsm4[j] = wt4[qq * (27 * 4 * OH) + j];
        __syncthreads();

        // scatter over k-sorted taps: 4 b128 weight reads (mostly broadcast) +
        // 16 FMA + 1 ds_add per (tap, oo)
        for (int j = slot; j < nt; j += 64) {
            unsigned tap = (unsigned)((j < TAPC) ? taps_s[j] : tapbuf[gs + j]);
            int pos = tap & 511;
            int k = (tap >> 9) & 31;
            int src = tap >> 14;
            const float4* fp = feats4 + (size_t)src * 4;   // broadcast across 8 oo lanes
            float4 f0 = fp[0], f1 = fp[1], f2 = fp[2], f3 = fp[3];
            const float4* wp = &wsm4[k * 32 + oo];
            float4 q0 = wp[0], q1 = wp[8], q2 = wp[16], q3 = wp[24];
            float acc = q0.x * f0.x + q0.y * f0.y + q0.z * f0.z + q0.w * f0.w
                      + q1.x * f1.x + q1.y * f1.y + q1.z * f1.z + q1.w * f1.w
                      + q2.x * f2.x + q2.y * f2.y + q2.z * f2.z + q2.w * f2.w
                      + q3.x * f3.x + q3.y * f3.y + q3.z * f3.z + q3.w * f3.w;
            atomicAdd(&tile[pos * TROW + oo], acc);
        }
        __syncthreads();

        // D1: BN partial stats (8 LDS reads + 6 shuffles per thread)
        float s1 = 0.f, s2 = 0.f;
        for (int p = slot; p < TPOS; p += 64) {
            float sv = tile[p * TROW + oo];
            s1 += sv;
            s2 += sv * sv;
        }
        s1 += __shfl_xor(s1, 8);  s2 += __shfl_xor(s2, 8);
        s1 += __shfl_xor(s1, 16); s2 += __shfl_xor(s2, 16);
        s1 += __shfl_xor(s1, 32); s2 += __shfl_xor(s2, 32);
        if (lane < OH) { wsum[wave][lane] = s1; wsq[wave][lane] = s2; }

        // D2: write pre-norm output; stride-9 scalar LDS reads conflict-free
#pragma unroll
        for (int i = 0; i < OH; ++i)
            out[(size_t)(obase + i) * DHW_ + outb] = tile[posD + i];
        __syncthreads();

        if (t < OH) {
            float a = 0.f, b = 0.f;
#pragma unroll
            for (int wv = 0; wv < 8; ++wv) { a += wsum[wv][t]; b += wsq[wv][t]; }
            atomicAdd(&stats[(obase + t) * SSLOT + sl], a);
            atomicAdd(&stats[COUT * SSLOT + (obase + t) * SSLOT + sl], b);
        }
    }
}

// ---------- K7: normalize + affine + ReLU (BYTE-IDENTICAL to R9 — control) ----------
__global__ void __launch_bounds__(256) norm_kernel(float* __restrict__ out,
                                                   const float* __restrict__ stats,
                                                   const float* __restrict__ gamma,
                                                   const float* __restrict__ beta) {
    __shared__ float sAB[2];
    int t = threadIdx.x;
    int bid = blockIdx.x;
    int c = bid >> 7;
    if (t < 64) {
        float a = stats[c * SSLOT + t];
        float b = stats[COUT * SSLOT + c * SSLOT + t];
        a += __shfl_xor(a, 1);  b += __shfl_xor(b, 1);
        a += __shfl_xor(a, 2);  b += __shfl_xor(b, 2);
        a += __shfl_xor(a, 4);  b += __shfl_xor(b, 4);
        a += __shfl_xor(a, 8);  b += __shfl_xor(b, 8);
        a += __shfl_xor(a, 16); b += __shfl_xor(b, 16);
        a += __shfl_xor(a, 32); b += __shfl_xor(b, 32);
        if (t == 0) {
            float n = (float)DHW_;
            float m1 = a / n, m2 = b / n;
            float var = fmaxf(m2 - m1 * m1, 0.f);
            float inv = rsqrtf(var + EPS_);
            float A = gamma[c] * inv;
            sAB[0] = A;
            sAB[1] = -m1 * A + beta[c];
        }
    }
    __syncthreads();
    float A = sAB[0], B = sAB[1];
    const int CH4 = DHW_ / 4;                        // 524288
    int base4 = c * CH4 + (bid & 127) * (CH4 / 128); // 4096 float4 per block
    float4* o4 = (float4*)out;
#pragma unroll
    for (int i = 0; i < 16; ++i) {
        int idx4 = base4 + i * 256 + t;
        float4 x = o4[idx4];
        x.x = fmaxf(x.x * A + B, 0.f);
        x.y = fmaxf(x.y * A + B, 0.f);
        x.z = fmaxf(x.z * A + B, 0.f);
        x.w = fmaxf(x.w * A + B, 0.f);
        o4[idx4] = x;
    }
}

extern "C" void kernel_launch(void* const* d_in, const int* in_sizes, int n_in,
                              void* d_out, int out_size, void* d_ws, size_t ws_size,
                              hipStream_t stream) {
    const float* voxels  = (const float*)d_in[0];
    const int*   indices = (const int*)  d_in[1];
    const float* conv_w  = (const float*)d_in[2];
    const float* gamma   = (const float*)d_in[4];
    const float* beta    = (const float*)d_in[5];
    float* out = (float*)d_out;

    // Workspace layout: R4-proven extents (tapbuf last). bar lives in the reserved
    // mi region (unused since R5's norm fusion).
    float4* wt4      = (float4*)d_ws;                        // 3456 float4 (55,296 B)
    float*  stats    = (float*)(wt4 + WTN);                  // 2*COUT*SSLOT floats (16,384 B)
    int*    bar      = (int*)(stats + 2 * COUT * SSLOT);     // in old mi region (256 B)
    int*    tapcnt   = (int*)(stats + 2 * COUT * SSLOT + 2 * COUT); // NT ints
    int*    tapstart = tapcnt + NT;                          // NT ints
    int*    tapcur   = tapstart + NT;                        // NT ints
    float4* feats4   = (float4*)(tapcur + NT);               // V*4 float4 (2.56 MB)
    int*    tapbuf   = (int*)(feats4 + (size_t)V_ * 4);      // <= V*27 ints, prefix used

    hipMemsetAsync(bar, 0, 16, stream);

    prep_all_kernel<<<NBLK_A, 256, 0, stream>>>(indices, tapcnt, conv_w, wt4,
                                                voxels, feats4, tapstart, tapcur,
                                                stats, tapbuf, bar);

    tile_conv_kernel<<<NT, TCT, 0, stream>>>(feats4, wt4, tapstart, tapcnt, tapbuf,
                                             stats, out);

    norm_kernel<<<COUT * 128, 256, 0, stream>>>(out, stats, gamma, beta);
}

// Round 11
// 643.058 us; speedup vs baseline: 1.3577x; 1.3577x over previous
//
#include <hip/hip_runtime.h>

#define D_   32
#define H_   256
#define W_   256
#define HW_  (H_ * W_)
#define DHW_ (D_ * H_ * W_)   // 2097152
#define V_   40000
#define CIN  16
#define COUT 32
#define P_   32
#define EPS_ 1e-5f

#define TD 2
#define TH 8
#define TW 32
#define NTX (W_ / TW)          // 8
#define NTY (H_ / TH)          // 32
#define NTZ (D_ / TD)          // 16
#define NT  (NTX * NTY * NTZ)  // 4096 tiles
#define TPOS (TD * TH * TW)    // 512
#define OH 8                   // channels per quarter
#define NQ (COUT / OH)         // 4
#define TROW 9                 // padded LDS row stride (odd -> conflict-free strided reads)
#define TCT 512                // threads per tile_conv block (8 waves)
#define SSLOT 64               // stats de-contention slots per channel
#define TAPC 640               // LDS-staged taps per tile (mean ~257; overflow reads global)
#define WTN  (NQ * 27 * 4 * OH)            // 3456 transpose items
#define WTBLK ((WTN + 255) / 256)          // 14 transpose blocks
#define CBLK  (V_ * 8 / 256)               // 1250 count/fill blocks (V*8 = 320000 exact)
#define FPBLK (V_ * CIN / 256)             // 2500 featpack blocks (V*16 = 640000 exact)

// ---------- K1: fused prep: 8x-parallel tap-count | weight transpose | 16x featpack ----------
__global__ void prep_kernel(const int* __restrict__ idxs, int* __restrict__ tapcnt,
                            const float* __restrict__ conv_w, float4* __restrict__ wt4,
                            const float* __restrict__ vox, float* __restrict__ feats) {
    int b = blockIdx.x;
    int t = threadIdx.x;
    if (b < CBLK) {
        // role A: tap count, one thread per (voxel, region-octant)
        int idx = b * 256 + t;
        int v = idx >> 3, r = idx & 7;
        int w = idxs[3 * v], h = idxs[3 * v + 1], d = idxs[3 * v + 2];
        if (!((unsigned)w < W_ && (unsigned)h < H_ && (unsigned)d < D_)) return;
        int dlo = max(d - 1, 0), dhi = min(d + 1, D_ - 1);
        int hlo = max(h - 1, 0), hhi = min(h + 1, H_ - 1);
        int wlo = max(w - 1, 0), whi = min(w + 1, W_ - 1);
        int tz = dlo / TD + ((r >> 2) & 1);
        int ty = hlo / TH + ((r >> 1) & 1);
        int tx = wlo / TW + (r & 1);
        if (tz > dhi / TD || ty > hhi / TH || tx > whi / TW) return;
        int zl = max(dlo, tz * TD), zh = min(dhi, tz * TD + TD - 1);
        int yl = max(hlo, ty * TH), yh = min(hhi, ty * TH + TH - 1);
        int xl = max(wlo, tx * TW), xh = min(whi, tx * TW + TW - 1);
        int cnt = (zh - zl + 1) * (yh - yl + 1) * (xh - xl + 1);
        atomicAdd(&tapcnt[tz * NTY * NTX + ty * NTX + tx], cnt);
        return;
    }
    b -= CBLK;
    if (b < WTBLK) {
        // role B: weight transpose wt4[((q*27+k)*4+jj)*8+oo] = {conv_w[o][4jj+i][k]}
        int n = b * 256 + t;
        if (n < WTN) {
            int oo = n & 7;
            int jj = (n >> 3) & 3;
            int m  = n >> 5;            // quarter*27 + k
            int k  = m % 27;
            int quarter = m / 27;
            int o = quarter * OH + oo;
            float4 wv;
            wv.x = conv_w[(o * CIN + 4 * jj + 0) * 27 + k];
            wv.y = conv_w[(o * CIN + 4 * jj + 1) * 27 + k];
            wv.z = conv_w[(o * CIN + 4 * jj + 2) * 27 + k];
            wv.w = conv_w[(o * CIN + 4 * jj + 3) * 27 + k];
            wt4[n] = wv;
        }
        return;
    }
    b -= WTBLK;
    // role C: featpack, one thread per (v, channel): read 128 B contiguous, store 1 float.
    // Wave reads 32 KB contiguous; stores perfectly coalesced.
    int idx = b * 256 + t;                 // = v*16 + c, in [0, V_*16)
    const float4* p = (const float4*)(vox + (size_t)idx * P_);
    float s = 0.f;
#pragma unroll
    for (int j = 0; j < P_ / 4; ++j) {
        float4 tv = p[j];
        s += tv.x + tv.y + tv.z + tv.w;
    }
    feats[idx] = s * (1.0f / (float)P_);
}

// ---------- K2: exclusive prefix over 4096 tiles ----------
__global__ void scan_kernel(const int* __restrict__ counts, int* __restrict__ starts,
                            int* __restrict__ cursor) {
    __shared__ int part[256];
    int t = threadIdx.x;
    int base = t * 16;
    int s = 0;
    for (int j = 0; j < 16; ++j) s += counts[base + j];
    part[t] = s;
    __syncthreads();
    for (int off = 1; off < 256; off <<= 1) {
        int val = part[t];
        int add = (t >= off) ? part[t - off] : 0;
        __syncthreads();
        part[t] = val + add;
        __syncthreads();
    }
    int run = (t > 0) ? part[t - 1] : 0;
    for (int j = 0; j < 16; ++j) {
        starts[base + j] = run;
        cursor[base + j] = run;
        run += counts[base + j];
    }
}

// ---------- K3: tap fill, one thread per (voxel, region-octant) ----------
// tap word = (v<<14) | (k<<9) | pos
__global__ void tap_fill_kernel(const int* __restrict__ idxs, int* __restrict__ cursor,
                                int* __restrict__ tapbuf) {
    int idx = blockIdx.x * 256 + threadIdx.x;
    int v = idx >> 3, r = idx & 7;
    int w = idxs[3 * v], h = idxs[3 * v + 1], d = idxs[3 * v + 2];
    if (!((unsigned)w < W_ && (unsigned)h < H_ && (unsigned)d < D_)) return;
    int dlo = max(d - 1, 0), dhi = min(d + 1, D_ - 1);
    int hlo = max(h - 1, 0), hhi = min(h + 1, H_ - 1);
    int wlo = max(w - 1, 0), whi = min(w + 1, W_ - 1);
    int tz = dlo / TD + ((r >> 2) & 1);
    int ty = hlo / TH + ((r >> 1) & 1);
    int tx = wlo / TW + (r & 1);
    if (tz > dhi / TD || ty > hhi / TH || tx > whi / TW) return;
    int zl = max(dlo, tz * TD), zh = min(dhi, tz * TD + TD - 1);
    int yl = max(hlo, ty * TH), yh = min(hhi, ty * TH + TH - 1);
    int xl = max(wlo, tx * TW), xh = min(whi, tx * TW + TW - 1);
    int cnt = (zh - zl + 1) * (yh - yl + 1) * (xh - xl + 1);
    int p = atomicAdd(&cursor[tz * NTY * NTX + ty * NTX + tx], cnt);
    for (int dq = zl; dq <= zh; ++dq)
        for (int hq = yl; hq <= yh; ++hq)
            for (int wq = xl; wq <= xh; ++wq) {
                int k = ((d - dq + 1) * 3 + (h - hq + 1)) * 3 + (w - wq + 1);
                int pos = ((dq & (TD - 1)) * TH + (hq & (TH - 1))) * TW + (wq & (TW - 1));
                tapbuf[p++] = (v << 14) | (k << 9) | pos;
            }
}

// ---------- K5: tile conv (BYTE-IDENTICAL to R9 — control) ----------
__global__ void __launch_bounds__(TCT, 8) tile_conv_kernel(
    const float4* __restrict__ feats4, const float4* __restrict__ wt4,
    const int* __restrict__ tapstart, const int* __restrict__ tapcnt,
    const int* __restrict__ tapbuf, float* __restrict__ stats,
    float* __restrict__ out)
{
    __shared__ float  tile[TPOS * TROW];   // 18432 B
    __shared__ float4 wsm4[27 * 4 * OH];   // 13824 B, [k*32 + jj*8 + oo]
    __shared__ int    taps_l[TAPC];        //  2560 B (staging)
    __shared__ int    taps_s[TAPC];        //  2560 B (k-sorted)
    __shared__ int    khist[32];           //   128 B (hist -> cursor)
    __shared__ float  wsum[8][OH], wsq[8][OH];

    int t = threadIdx.x;
    int tile_id = blockIdx.x;
    int gs = tapstart[tile_id];
    int nt = tapcnt[tile_id];
    int tx = tile_id % NTX, ty = (tile_id / NTX) % NTY, tz = tile_id / (NTX * NTY);
    int w0 = tx * TW, h0 = ty * TH, d0 = tz * TD;
    int sl = tile_id & (SSLOT - 1);

    // stage tap list + counting-sort by k (done once, reused by all 4 quarters)
    int ntl = min(nt, TAPC);
    if (t < 32) khist[t] = 0;
    for (int j = t; j < ntl; j += TCT) taps_l[j] = tapbuf[gs + j];
    __syncthreads();
    for (int j = t; j < ntl; j += TCT)
        atomicAdd(&khist[(taps_l[j] >> 9) & 31], 1);
    __syncthreads();
    if (t < 64) {                           // wave-0 exclusive scan over 27 bins
        int x = (t < 27) ? khist[t] : 0;
        int orig = x;
#pragma unroll
        for (int off = 1; off < 32; off <<= 1) {
            int y = __shfl_up(x, off);
            if (t >= off) x += y;
        }
        if (t < 27) khist[t] = x - orig;    // becomes the scatter cursor
    }
    __syncthreads();
    for (int j = t; j < ntl; j += TCT) {
        int tap = taps_l[j];
        int p = atomicAdd(&khist[(tap >> 9) & 31], 1);
        taps_s[p] = tap;
    }
    __syncthreads();

    int oo = t & 7, slot = t >> 3;          // scatter + D1 mapping
    int wave = t >> 6, lane = t & 63;
    int wl = t & 31, rem = t >> 5;          // D2 mapping (rem 0..15)
    size_t outb = (size_t)(d0 + (rem >> 3)) * HW_ + (size_t)(h0 + (rem & 7)) * W_
                + (size_t)(w0 + wl);
    int posD = (rem * TW + wl) * TROW;

#pragma unroll
    for (int qq = 0; qq < NQ; ++qq) {
        int obase = qq * OH;
        // stage: zero tile + this quarter's weights (linear layout)
        for (int j = t; j < TPOS * TROW / 4; j += TCT)
            ((float4*)tile)[j] = make_float4(0, 0, 0, 0);
        for (int j = t; j < 27 * 4 * OH; j += TCT)
            wsm4[j] = wt4[qq * (27 * 4 * OH) + j];
        __syncthreads();

        // scatter over k-sorted taps: 4 b128 weight reads (mostly broadcast) +
        // 16 FMA + 1 ds_add per (tap, oo)
        for (int j = slot; j < nt; j += 64) {
            unsigned tap = (unsigned)((j < TAPC) ? taps_s[j] : tapbuf[gs + j]);
            int pos = tap & 511;
            int k = (tap >> 9) & 31;
            int src = tap >> 14;
            const float4* fp = feats4 + (size_t)src * 4;   // broadcast across 8 oo lanes
            float4 f0 = fp[0], f1 = fp[1], f2 = fp[2], f3 = fp[3];
            const float4* wp = &wsm4[k * 32 + oo];
            float4 q0 = wp[0], q1 = wp[8], q2 = wp[16], q3 = wp[24];
            float acc = q0.x * f0.x + q0.y * f0.y + q0.z * f0.z + q0.w * f0.w
                      + q1.x * f1.x + q1.y * f1.y + q1.z * f1.z + q1.w * f1.w
                      + q2.x * f2.x + q2.y * f2.y + q2.z * f2.z + q2.w * f2.w
                      + q3.x * f3.x + q3.y * f3.y + q3.z * f3.z + q3.w * f3.w;
            atomicAdd(&tile[pos * TROW + oo], acc);
        }
        __syncthreads();

        // D1: BN partial stats (8 LDS reads + 6 shuffles per thread)
        float s1 = 0.f, s2 = 0.f;
        for (int p = slot; p < TPOS; p += 64) {
            float sv = tile[p * TROW + oo];
            s1 += sv;
            s2 += sv * sv;
        }
        s1 += __shfl_xor(s1, 8);  s2 += __shfl_xor(s2, 8);
        s1 += __shfl_xor(s1, 16); s2 += __shfl_xor(s2, 16);
        s1 += __shfl_xor(s1, 32); s2 += __shfl_xor(s2, 32);
        if (lane < OH) { wsum[wave][lane] = s1; wsq[wave][lane] = s2; }

        // D2: write pre-norm output; stride-9 scalar LDS reads conflict-free
#pragma unroll
        for (int i = 0; i < OH; ++i)
            out[(size_t)(obase + i) * DHW_ + outb] = tile[posD + i];
        __syncthreads();

        if (t < OH) {
            float a = 0.f, b = 0.f;
#pragma unroll
            for (int wv = 0; wv < 8; ++wv) { a += wsum[wv][t]; b += wsq[wv][t]; }
            atomicAdd(&stats[(obase + t) * SSLOT + sl], a);
            atomicAdd(&stats[COUT * SSLOT + (obase + t) * SSLOT + sl], b);
        }
    }
}

// ---------- K7: normalize + affine + ReLU (BYTE-IDENTICAL to R9 — control) ----------
__global__ void __launch_bounds__(256) norm_kernel(float* __restrict__ out,
                                                   const float* __restrict__ stats,
                                                   const float* __restrict__ gamma,
                                                   const float* __restrict__ beta) {
    __shared__ float sAB[2];
    int t = threadIdx.x;
    int bid = blockIdx.x;
    int c = bid >> 7;
    if (t < 64) {
        float a = stats[c * SSLOT + t];
        float b = stats[COUT * SSLOT + c * SSLOT + t];
        a += __shfl_xor(a, 1);  b += __shfl_xor(b, 1);
        a += __shfl_xor(a, 2);  b += __shfl_xor(b, 2);
        a += __shfl_xor(a, 4);  b += __shfl_xor(b, 4);
        a += __shfl_xor(a, 8);  b += __shfl_xor(b, 8);
        a += __shfl_xor(a, 16); b += __shfl_xor(b, 16);
        a += __shfl_xor(a, 32); b += __shfl_xor(b, 32);
        if (t == 0) {
            float n = (float)DHW_;
            float m1 = a / n, m2 = b / n;
            float var = fmaxf(m2 - m1 * m1, 0.f);
            float inv = rsqrtf(var + EPS_);
            float A = gamma[c] * inv;
            sAB[0] = A;
            sAB[1] = -m1 * A + beta[c];
        }
    }
    __syncthreads();
    float A = sAB[0], B = sAB[1];
    const int CH4 = DHW_ / 4;                        // 524288
    int base4 = c * CH4 + (bid & 127) * (CH4 / 128); // 4096 float4 per block
    float4* o4 = (float4*)out;
#pragma unroll
    for (int i = 0; i < 16; ++i) {
        int idx4 = base4 + i * 256 + t;
        float4 x = o4[idx4];
        x.x = fmaxf(x.x * A + B, 0.f);
        x.y = fmaxf(x.y * A + B, 0.f);
        x.z = fmaxf(x.z * A + B, 0.f);
        x.w = fmaxf(x.w * A + B, 0.f);
        o4[idx4] = x;
    }
}

extern "C" void kernel_launch(void* const* d_in, const int* in_sizes, int n_in,
                              void* d_out, int out_size, void* d_ws, size_t ws_size,
                              hipStream_t stream) {
    const float* voxels  = (const float*)d_in[0];
    const int*   indices = (const int*)  d_in[1];
    const float* conv_w  = (const float*)d_in[2];
    const float* gamma   = (const float*)d_in[4];
    const float* beta    = (const float*)d_in[5];
    float* out = (float*)d_out;

    // Workspace layout: same extents as the R4-proven layout (tapbuf last; written
    // extent ~6.89 MB < ws_size). stats and tapcnt adjacent -> single 32 KB memset.
    float4* wt4      = (float4*)d_ws;                        // 3456 float4 (55,296 B)
    float*  stats    = (float*)(wt4 + WTN);                  // 2*COUT*SSLOT floats (16,384 B)
    int*    tapcnt   = (int*)(stats + 2 * COUT * SSLOT);     // NT ints (16,384 B)
    int*    tapstart = tapcnt + NT;                          // NT ints
    int*    tapcur   = tapstart + NT;                        // NT ints
    float*  feats    = (float*)(tapcur + NT);                // V*16 floats (2.56 MB), 16B-aligned
    int*    tapbuf   = (int*)(feats + (size_t)V_ * CIN);     // <= V*27 ints, prefix used

    hipMemsetAsync(stats, 0, (2 * COUT * SSLOT + NT) * sizeof(float), stream);

    prep_kernel<<<CBLK + WTBLK + FPBLK, 256, 0, stream>>>(indices, tapcnt, conv_w, wt4,
                                                          voxels, feats);
    scan_kernel<<<1, 256, 0, stream>>>(tapcnt, tapstart, tapcur);
    tap_fill_kernel<<<CBLK, 256, 0, stream>>>(indices, tapcur, tapbuf);

    tile_conv_kernel<<<NT, TCT, 0, stream>>>((const float4*)feats, wt4, tapstart, tapcnt,
                                             tapbuf, stats, out);

    norm_kernel<<<COUT * 128, 256, 0, stream>>>(out, stats, gamma, beta);
}